// Round 3
// baseline (420.441 us; speedup 1.0000x reference)
//
#include <hip/hip_runtime.h>

#define DEVINL __device__ __forceinline__

typedef __attribute__((ext_vector_type(8))) short bf16x8;
typedef __attribute__((ext_vector_type(4))) short bf16x4;
typedef __attribute__((ext_vector_type(4))) float f32x4;

DEVINL short f2bf(float f) {
  union { float f; unsigned u; } v; v.f = f;
  unsigned r = v.u + 0x7fffu + ((v.u >> 16) & 1u);
  return (short)(r >> 16);
}
DEVINL float bf2f(short h) {
  union { unsigned u; float f; } v;
  v.u = ((unsigned)(unsigned short)h) << 16;
  return v.f;
}

DEVINL float gelu_f(float x) {
  // gelu(x) = x*(0.5 + 0.39894228*x*(1 - x^2/6 + x^4/40)); |x|<0.05 here
  float t2 = x * x;
  float q  = __builtin_fmaf(t2, 0.025f, -0.16666667f);
  float p  = __builtin_fmaf(t2, q, 1.0f);
  float u  = 0.39894228f * x;
  float w  = __builtin_fmaf(u, p, 0.5f);
  return x * w;
}

DEVINL void gload_lds16(const void* g, void* l) {
  __builtin_amdgcn_global_load_lds((__attribute__((address_space(1))) const void*)g,
                                   (__attribute__((address_space(3))) void*)l, 16, 0, 0);
}

// ---------------- cast fp32 -> bf16 (with optional scale) ----------------
__global__ __launch_bounds__(256) void cast_kernel(const float* __restrict__ src,
                                                   short* __restrict__ dst,
                                                   int n4, float scale) {
  int i = blockIdx.x * blockDim.x + threadIdx.x;
  if (i >= n4) return;
  float4 v = reinterpret_cast<const float4*>(src)[i];
  short4 o;
  o.x = f2bf(v.x * scale); o.y = f2bf(v.y * scale);
  o.z = f2bf(v.z * scale); o.w = f2bf(v.w * scale);
  reinterpret_cast<short4*>(dst)[i] = o;
}

// ---------------- GEMM: C[M][Ncols] = A[M][512] * B[Ncols][512]^T ----------------
template<int MODE>
__global__ __launch_bounds__(256) void gemm_k512(
    const short* __restrict__ A, const short* __restrict__ Bw, int nTilesN,
    short* __restrict__ qk_out, short* __restrict__ vt_out,
    float* __restrict__ f_out, const float* __restrict__ bias) {
  __shared__ short As[128 * 64];
  __shared__ short Bs[128 * 64];
  const int tid = threadIdx.x;
  const int lane = tid & 63, wave = tid >> 6;
  const int wm = wave >> 1, wn = wave & 1;
  const int l16 = lane & 15, l4 = lane >> 4;
  const int cpx = gridDim.x >> 3;
  const int swz = (blockIdx.x & 7) * cpx + (blockIdx.x >> 3);
  const int bm = swz / nTilesN, bn = swz % nTilesN;

  f32x4 acc[4][4] = {};

  for (int kt = 0; kt < 8; ++kt) {
#pragma unroll
    for (int i = 0; i < 4; ++i) {
      int Lofs = (i * 4 + wave) * 1024;
      int L = Lofs + lane * 16;
      int row = L >> 7;
      int lc = ((L & 127) >> 4) ^ (row & 7);
      gload_lds16(A + (bm * 128 + row) * 512 + kt * 64 + lc * 8, (char*)As + Lofs);
      gload_lds16(Bw + (bn * 128 + row) * 512 + kt * 64 + lc * 8, (char*)Bs + Lofs);
    }
    __syncthreads();
#pragma unroll
    for (int ks = 0; ks < 2; ++ks) {
      bf16x8 af[4], bfr[4];
#pragma unroll
      for (int mi = 0; mi < 4; ++mi) {
        int r = wm * 64 + mi * 16 + l16;
        int c = (ks * 4 + l4) ^ (r & 7);
        af[mi] = *reinterpret_cast<const bf16x8*>((const char*)As + r * 128 + c * 16);
      }
#pragma unroll
      for (int ni = 0; ni < 4; ++ni) {
        int r = wn * 64 + ni * 16 + l16;
        int c = (ks * 4 + l4) ^ (r & 7);
        bfr[ni] = *reinterpret_cast<const bf16x8*>((const char*)Bs + r * 128 + c * 16);
      }
#pragma unroll
      for (int mi = 0; mi < 4; ++mi)
#pragma unroll
        for (int ni = 0; ni < 4; ++ni)
          acc[mi][ni] = __builtin_amdgcn_mfma_f32_16x16x32_bf16(af[mi], bfr[ni], acc[mi][ni], 0, 0, 0);
    }
    __syncthreads();
  }

  const int colbase = bn * 128 + wn * 64;
  const int rowbase = bm * 128 + wm * 64;
  if (MODE == 0) {
    if (colbase < 1024) {
#pragma unroll
      for (int mi = 0; mi < 4; ++mi)
#pragma unroll
        for (int ni = 0; ni < 4; ++ni)
#pragma unroll
          for (int i = 0; i < 4; ++i) {
            int row = rowbase + mi * 16 + l4 * 4 + i;
            int col = colbase + ni * 16 + l16;
            qk_out[row * 1024 + col] = f2bf(acc[mi][ni][i]);
          }
    } else {
#pragma unroll
      for (int mi = 0; mi < 4; ++mi)
#pragma unroll
        for (int ni = 0; ni < 4; ++ni)
#pragma unroll
          for (int i = 0; i < 4; ++i) {
            int row = rowbase + mi * 16 + l4 * 4 + i;
            int o = colbase + ni * 16 + l16 - 1024;
            int h = o >> 6, d = o & 63;
            int b = row >> 8, n = row & 255;
            vt_out[((b * 8 + h) * 64 + d) * 256 + n] = f2bf(acc[mi][ni][i]);
          }
    }
  } else {
#pragma unroll
    for (int mi = 0; mi < 4; ++mi)
#pragma unroll
      for (int ni = 0; ni < 4; ++ni)
#pragma unroll
        for (int i = 0; i < 4; ++i) {
          int row = rowbase + mi * 16 + l4 * 4 + i;
          int col = colbase + ni * 16 + l16;
          f_out[row * 512 + col] = acc[mi][ni][i] + bias[col];
        }
  }
}

// ---------------- fused attention ----------------
// grid = B*16 blocks of 512 threads (8 waves, wave = head)
// S LDS: logical [R = h*16 + r][m], bf16; chunk-swizzle c' = (m>>3) ^ (R&15)
DEVINL char* sPtr(short* S, int R, int m) {
  return reinterpret_cast<char*>(S) + (R << 9) + ((((m >> 3) ^ (R & 15)) << 4) | ((m & 7) << 1));
}
DEVINL char* sChunk(short* S, int R, int c) {
  return reinterpret_cast<char*>(S) + (R << 9) + (((c ^ (R & 15)) << 4));
}

__global__ __launch_bounds__(512, 4) void attn_fused(
    const short* __restrict__ qk,   // [16384][1024] bf16 (q | k*scale)
    const short* __restrict__ vt,   // [(b*8+h)][64][256] bf16
    const float* __restrict__ We,   // [16][8]
    const float* __restrict__ Ws,   // [8][16]
    const int* __restrict__ eidx,   // [B][2][2048]
    short* __restrict__ U,          // [16384][512] bf16  (v - A v)
    float* __restrict__ ea) {       // [8][131072]
  __shared__ short S[32768];        // 64 KB, holds logits then exp(logits)
  __shared__ float WeS[128];
  __shared__ float WsS[128];
  __shared__ float invS[128];       // 1/rowsum per (h, local row)
  const int tid = threadIdx.x;
  const int lane = tid & 63;
  const int h = tid >> 6;           // wave = head
  const int l16 = lane & 15, l4 = lane >> 4;
  const int swz = (blockIdx.x & 7) * 128 + (blockIdx.x >> 3);  // XCD swizzle
  const int b = swz >> 4;
  const int r0 = (swz & 15) << 4;

  if (tid < 128) WeS[tid] = We[tid];
  else if (tid < 256) WsS[tid - 128] = Ws[tid - 128];

  // ---- QK^T : one head per wave ----
  {
    const int qrow = (b * 256 + r0 + l16) * 1024 + h * 64;
    bf16x8 aq0 = *reinterpret_cast<const bf16x8*>(qk + qrow + l4 * 8);
    bf16x8 aq1 = *reinterpret_cast<const bf16x8*>(qk + qrow + 32 + l4 * 8);
#pragma unroll 4
    for (int mt = 0; mt < 16; ++mt) {
      f32x4 acc = {0.f, 0.f, 0.f, 0.f};
      const int krow = (b * 256 + mt * 16 + l16) * 1024 + 512 + h * 64;
      bf16x8 bk0 = *reinterpret_cast<const bf16x8*>(qk + krow + l4 * 8);
      bf16x8 bk1 = *reinterpret_cast<const bf16x8*>(qk + krow + 32 + l4 * 8);
      acc = __builtin_amdgcn_mfma_f32_16x16x32_bf16(aq0, bk0, acc, 0, 0, 0);
      acc = __builtin_amdgcn_mfma_f32_16x16x32_bf16(aq1, bk1, acc, 0, 0, 0);
#pragma unroll
      for (int i = 0; i < 4; ++i)
        *reinterpret_cast<short*>(sPtr(S, h * 16 + l4 * 4 + i, mt * 16 + l16)) = f2bf(acc[i]);
    }
  }
  __syncthreads();

  // ---- mix (expand->gelu->squeeze) + exp + row-sum, half-chunk at a time ----
  {
    const int r = tid >> 5;        // local row 0..15
    const int j = tid & 31;        // 8-col chunk 0..31
    float psum[8] = {0.f, 0.f, 0.f, 0.f, 0.f, 0.f, 0.f, 0.f};
#pragma unroll
    for (int half = 0; half < 2; ++half) {
      bf16x4 ph[8];
#pragma unroll
      for (int hh = 0; hh < 8; ++hh)
        ph[hh] = *reinterpret_cast<const bf16x4*>(sChunk(S, hh * 16 + r, j) + half * 8);
      bf16x4 ot[8];
#pragma unroll
      for (int p = 0; p < 4; ++p) {
        float s[8];
#pragma unroll
        for (int hh = 0; hh < 8; ++hh) s[hh] = bf2f(ph[hh][p]);
        float g[16];
#pragma unroll
        for (int e = 0; e < 16; ++e) {
          float a = 0.f;
#pragma unroll
          for (int hh = 0; hh < 8; ++hh) a = __builtin_fmaf(WeS[e * 8 + hh], s[hh], a);
          g[e] = gelu_f(a);
        }
#pragma unroll
        for (int hh = 0; hh < 8; ++hh) {
          float a = 0.f;
#pragma unroll
          for (int e = 0; e < 16; ++e) a = __builtin_fmaf(WsS[hh * 16 + e], g[e], a);
          float ex = __expf(a);
          psum[hh] += ex;
          ot[hh][p] = f2bf(ex);
        }
      }
#pragma unroll
      for (int hh = 0; hh < 8; ++hh)
        *reinterpret_cast<bf16x4*>(sChunk(S, hh * 16 + r, j) + half * 8) = ot[hh];
    }
#pragma unroll
    for (int off = 1; off < 32; off <<= 1)
#pragma unroll
      for (int hh = 0; hh < 8; ++hh) psum[hh] += __shfl_xor(psum[hh], off);
    if (j == 0) {
#pragma unroll
      for (int hh = 0; hh < 8; ++hh) invS[hh * 16 + r] = 1.0f / psum[hh];
    }
  }
  __syncthreads();

  // ---- edge gather: ea = exp * inv ----
  {
    const int* ei = eidx + b * 4096;
#pragma unroll
    for (int jj = 0; jj < 4; ++jj) {
      int e = jj * 512 + tid;
      int s = ei[e];
      int t = ei[2048 + e];
      int rr = s - r0;
      if ((unsigned)rr < 16u) {
#pragma unroll
        for (int hh = 0; hh < 8; ++hh) {
          float a = bf2f(*reinterpret_cast<const short*>(sPtr(S, hh * 16 + rr, t))) * invS[hh * 16 + rr];
          ea[hh * 131072 + b * 2048 + e] = a;
        }
      }
    }
  }

  // ---- PV: Y = exp @ v ; U = v - Y*inv[row] ----
  {
    bf16x8 af[8];
#pragma unroll
    for (int ks = 0; ks < 8; ++ks)
      af[ks] = *reinterpret_cast<const bf16x8*>(sChunk(S, h * 16 + l16, ks * 4 + l4));
    const short* vb = vt + (b * 8 + h) * 16384;
#pragma unroll
    for (int nt = 0; nt < 4; ++nt) {
      f32x4 acc = {0.f, 0.f, 0.f, 0.f};
#pragma unroll
      for (int ks = 0; ks < 8; ++ks) {
        bf16x8 bv = *reinterpret_cast<const bf16x8*>(vb + (nt * 16 + l16) * 256 + ks * 32 + l4 * 8);
        acc = __builtin_amdgcn_mfma_f32_16x16x32_bf16(af[ks], bv, acc, 0, 0, 0);
      }
      bf16x4 vv = *reinterpret_cast<const bf16x4*>(vb + (nt * 16 + l16) * 256 + r0 + l4 * 4);
#pragma unroll
      for (int i = 0; i < 4; ++i) {
        int rl = l4 * 4 + i;
        int row = b * 256 + r0 + rl;
        int col = h * 64 + nt * 16 + l16;
        U[row * 512 + col] = f2bf(bf2f(vv[i]) - acc[i] * invS[h * 16 + rl]);
      }
    }
  }
}

extern "C" void kernel_launch(void* const* d_in, const int* in_sizes, int n_in,
                              void* d_out, int out_size, void* d_ws, size_t ws_size,
                              hipStream_t stream) {
  const float* x = (const float*)d_in[0];
  const int* eidx = (const int*)d_in[1];
  const float* Wq = (const float*)d_in[2];
  const float* Wk = (const float*)d_in[3];
  const float* Wv = (const float*)d_in[4];
  const float* We = (const float*)d_in[5];
  const float* Ws = (const float*)d_in[6];
  const float* Wo = (const float*)d_in[7];
  const float* bo = (const float*)d_in[8];
  float* out = (float*)d_out;

  char* ws = (char*)d_ws;
  short* x_bf  = (short*)(ws);              // 16 MB (aliased with U after gemm<0>)
  short* w_qkv = (short*)(ws + 16777216);   // 1.5 MB  [Wq; Wk*0.125; Wv]
  short* w_o   = (short*)(ws + 18350080);   // 0.5 MB
  short* qk    = (short*)(ws + 18874368);   // 32 MB
  short* vt    = (short*)(ws + 52428800);   // 16 MB
  short* Ub    = x_bf;

  cast_kernel<<<8192, 256, 0, stream>>>(x, x_bf, 2097152, 1.0f);
  cast_kernel<<<256, 256, 0, stream>>>(Wq, w_qkv, 65536, 1.0f);
  cast_kernel<<<256, 256, 0, stream>>>(Wk, w_qkv + 262144, 65536, 0.125f);
  cast_kernel<<<256, 256, 0, stream>>>(Wv, w_qkv + 524288, 65536, 1.0f);
  cast_kernel<<<256, 256, 0, stream>>>(Wo, w_o, 65536, 1.0f);

  gemm_k512<0><<<1536, 256, 0, stream>>>(x_bf, w_qkv, 12, qk, vt, nullptr, nullptr);
  attn_fused<<<1024, 512, 0, stream>>>(qk, vt, We, Ws, eidx, Ub, out + 8388608);
  gemm_k512<1><<<512, 256, 0, stream>>>(Ub, w_o, 4, nullptr, nullptr, out, bo);
}

// Round 4
// 191.690 us; speedup vs baseline: 2.1933x; 2.1933x over previous
//
#include <hip/hip_runtime.h>

#define DEVINL __device__ __forceinline__

typedef __attribute__((ext_vector_type(8))) short bf16x8;
typedef __attribute__((ext_vector_type(4))) short bf16x4;
typedef __attribute__((ext_vector_type(4))) float f32x4;

DEVINL short f2bf(float f) {
  union { float f; unsigned u; } v; v.f = f;
  unsigned r = v.u + 0x7fffu + ((v.u >> 16) & 1u);
  return (short)(r >> 16);
}
DEVINL float bf2f(short h) {
  union { unsigned u; float f; } v;
  v.u = ((unsigned)(unsigned short)h) << 16;
  return v.f;
}

DEVINL float gelu_f(float x) {
  // gelu(x) = x*(0.5 + 0.39894228*x*(1 - x^2/6 + x^4/40)); |x|<0.05 here
  float t2 = x * x;
  float q  = __builtin_fmaf(t2, 0.025f, -0.16666667f);
  float p  = __builtin_fmaf(t2, q, 1.0f);
  float u  = 0.39894228f * x;
  float w  = __builtin_fmaf(u, p, 0.5f);
  return x * w;
}

DEVINL void gload_lds16(const void* g, void* l) {
  __builtin_amdgcn_global_load_lds((__attribute__((address_space(1))) const void*)g,
                                   (__attribute__((address_space(3))) void*)l, 16, 0, 0);
}

// ---------------- cast fp32 -> bf16 (with optional scale) ----------------
__global__ __launch_bounds__(256) void cast_kernel(const float* __restrict__ src,
                                                   short* __restrict__ dst,
                                                   int n4, float scale) {
  int i = blockIdx.x * blockDim.x + threadIdx.x;
  if (i >= n4) return;
  float4 v = reinterpret_cast<const float4*>(src)[i];
  short4 o;
  o.x = f2bf(v.x * scale); o.y = f2bf(v.y * scale);
  o.z = f2bf(v.z * scale); o.w = f2bf(v.w * scale);
  reinterpret_cast<short4*>(dst)[i] = o;
}

// ---------------- GEMM: C[M][Ncols] = A[M][512] * B[Ncols][512]^T ----------------
template<int MODE>
__global__ __launch_bounds__(256) void gemm_k512(
    const short* __restrict__ A, const short* __restrict__ Bw, int nTilesN,
    short* __restrict__ qk_out, short* __restrict__ vt_out,
    float* __restrict__ f_out, const float* __restrict__ bias) {
  __shared__ short As[128 * 64];
  __shared__ short Bs[128 * 64];
  const int tid = threadIdx.x;
  const int lane = tid & 63, wave = tid >> 6;
  const int wm = wave >> 1, wn = wave & 1;
  const int l16 = lane & 15, l4 = lane >> 4;
  const int cpx = gridDim.x >> 3;
  const int swz = (blockIdx.x & 7) * cpx + (blockIdx.x >> 3);
  const int bm = swz / nTilesN, bn = swz % nTilesN;

  f32x4 acc[4][4] = {};

  for (int kt = 0; kt < 8; ++kt) {
#pragma unroll
    for (int i = 0; i < 4; ++i) {
      int Lofs = (i * 4 + wave) * 1024;
      int L = Lofs + lane * 16;
      int row = L >> 7;
      int lc = ((L & 127) >> 4) ^ (row & 7);
      gload_lds16(A + (bm * 128 + row) * 512 + kt * 64 + lc * 8, (char*)As + Lofs);
      gload_lds16(Bw + (bn * 128 + row) * 512 + kt * 64 + lc * 8, (char*)Bs + Lofs);
    }
    __syncthreads();
#pragma unroll
    for (int ks = 0; ks < 2; ++ks) {
      bf16x8 af[4], bfr[4];
#pragma unroll
      for (int mi = 0; mi < 4; ++mi) {
        int r = wm * 64 + mi * 16 + l16;
        int c = (ks * 4 + l4) ^ (r & 7);
        af[mi] = *reinterpret_cast<const bf16x8*>((const char*)As + r * 128 + c * 16);
      }
#pragma unroll
      for (int ni = 0; ni < 4; ++ni) {
        int r = wn * 64 + ni * 16 + l16;
        int c = (ks * 4 + l4) ^ (r & 7);
        bfr[ni] = *reinterpret_cast<const bf16x8*>((const char*)Bs + r * 128 + c * 16);
      }
#pragma unroll
      for (int mi = 0; mi < 4; ++mi)
#pragma unroll
        for (int ni = 0; ni < 4; ++ni)
          acc[mi][ni] = __builtin_amdgcn_mfma_f32_16x16x32_bf16(af[mi], bfr[ni], acc[mi][ni], 0, 0, 0);
    }
    __syncthreads();
  }

  const int colbase = bn * 128 + wn * 64;
  const int rowbase = bm * 128 + wm * 64;
  if (MODE == 0) {
    if (colbase < 1024) {
#pragma unroll
      for (int mi = 0; mi < 4; ++mi)
#pragma unroll
        for (int ni = 0; ni < 4; ++ni)
#pragma unroll
          for (int i = 0; i < 4; ++i) {
            int row = rowbase + mi * 16 + l4 * 4 + i;
            int col = colbase + ni * 16 + l16;
            qk_out[row * 1024 + col] = f2bf(acc[mi][ni][i]);
          }
    } else {
#pragma unroll
      for (int mi = 0; mi < 4; ++mi)
#pragma unroll
        for (int ni = 0; ni < 4; ++ni)
#pragma unroll
          for (int i = 0; i < 4; ++i) {
            int row = rowbase + mi * 16 + l4 * 4 + i;
            int o = colbase + ni * 16 + l16 - 1024;
            int h = o >> 6, d = o & 63;
            int b = row >> 8, n = row & 255;
            vt_out[((b * 8 + h) * 64 + d) * 256 + n] = f2bf(acc[mi][ni][i]);
          }
    }
  } else {
#pragma unroll
    for (int mi = 0; mi < 4; ++mi)
#pragma unroll
      for (int ni = 0; ni < 4; ++ni)
#pragma unroll
        for (int i = 0; i < 4; ++i) {
          int row = rowbase + mi * 16 + l4 * 4 + i;
          int col = colbase + ni * 16 + l16;
          f_out[row * 512 + col] = acc[mi][ni][i] + bias[col];
        }
  }
}

// ---------------- fused attention ----------------
// grid = B*16 blocks of 512 threads (8 waves, wave = head)
// S LDS: logical [R = h*16 + r][m], bf16; chunk-swizzle c' = (m>>3) ^ (R&15)
DEVINL char* sPtr(short* S, int R, int m) {
  return reinterpret_cast<char*>(S) + (R << 9) + ((((m >> 3) ^ (R & 15)) << 4) | ((m & 7) << 1));
}
DEVINL char* sChunk(short* S, int R, int c) {
  return reinterpret_cast<char*>(S) + (R << 9) + (((c ^ (R & 15)) << 4));
}

__global__ __launch_bounds__(512, 2) void attn_fused(
    const short* __restrict__ qk,   // [16384][1024] bf16 (q | k*scale)
    const short* __restrict__ vt,   // [(b*8+h)][64][256] bf16
    const float* __restrict__ We,   // [16][8]
    const float* __restrict__ Ws,   // [8][16]
    const int* __restrict__ eidx,   // [B][2][2048]
    short* __restrict__ U,          // [16384][512] bf16  (v - A v)
    float* __restrict__ ea) {       // [8][131072]
  __shared__ short S[32768];        // 64 KB, holds logits then exp(logits)
  __shared__ float WeS[128];
  __shared__ float WsS[128];
  __shared__ float invS[128];       // 1/rowsum per (h, local row)
  const int tid = threadIdx.x;
  const int lane = tid & 63;
  const int h = tid >> 6;           // wave = head
  const int l16 = lane & 15, l4 = lane >> 4;
  const int swz = (blockIdx.x & 7) * 128 + (blockIdx.x >> 3);  // XCD swizzle
  const int b = swz >> 4;
  const int r0 = (swz & 15) << 4;

  if (tid < 128) WeS[tid] = We[tid];
  else if (tid < 256) WsS[tid - 128] = Ws[tid - 128];

  // ---- QK^T : one head per wave ----
  {
    const int qrow = (b * 256 + r0 + l16) * 1024 + h * 64;
    bf16x8 aq0 = *reinterpret_cast<const bf16x8*>(qk + qrow + l4 * 8);
    bf16x8 aq1 = *reinterpret_cast<const bf16x8*>(qk + qrow + 32 + l4 * 8);
#pragma unroll 4
    for (int mt = 0; mt < 16; ++mt) {
      f32x4 acc = {0.f, 0.f, 0.f, 0.f};
      const int krow = (b * 256 + mt * 16 + l16) * 1024 + 512 + h * 64;
      bf16x8 bk0 = *reinterpret_cast<const bf16x8*>(qk + krow + l4 * 8);
      bf16x8 bk1 = *reinterpret_cast<const bf16x8*>(qk + krow + 32 + l4 * 8);
      acc = __builtin_amdgcn_mfma_f32_16x16x32_bf16(aq0, bk0, acc, 0, 0, 0);
      acc = __builtin_amdgcn_mfma_f32_16x16x32_bf16(aq1, bk1, acc, 0, 0, 0);
#pragma unroll
      for (int i = 0; i < 4; ++i)
        *reinterpret_cast<short*>(sPtr(S, h * 16 + l4 * 4 + i, mt * 16 + l16)) = f2bf(acc[i]);
    }
  }
  __syncthreads();

  // ---- mix (expand->gelu->squeeze) + exp + row-sum, half-chunk at a time ----
  {
    const int r = tid >> 5;        // local row 0..15
    const int j = tid & 31;        // 8-col chunk 0..31
    float psum[8] = {0.f, 0.f, 0.f, 0.f, 0.f, 0.f, 0.f, 0.f};
#pragma unroll
    for (int half = 0; half < 2; ++half) {
      bf16x4 ph[8];
#pragma unroll
      for (int hh = 0; hh < 8; ++hh)
        ph[hh] = *reinterpret_cast<const bf16x4*>(sChunk(S, hh * 16 + r, j) + half * 8);
      bf16x4 ot[8];
#pragma unroll
      for (int p = 0; p < 4; ++p) {
        float s[8];
#pragma unroll
        for (int hh = 0; hh < 8; ++hh) s[hh] = bf2f(ph[hh][p]);
        float g[16];
#pragma unroll
        for (int e = 0; e < 16; ++e) {
          float a = 0.f;
#pragma unroll
          for (int hh = 0; hh < 8; ++hh) a = __builtin_fmaf(WeS[e * 8 + hh], s[hh], a);
          g[e] = gelu_f(a);
        }
#pragma unroll
        for (int hh = 0; hh < 8; ++hh) {
          float a = 0.f;
#pragma unroll
          for (int e = 0; e < 16; ++e) a = __builtin_fmaf(WsS[hh * 16 + e], g[e], a);
          float ex = __expf(a);
          psum[hh] += ex;
          ot[hh][p] = f2bf(ex);
        }
      }
#pragma unroll
      for (int hh = 0; hh < 8; ++hh)
        *reinterpret_cast<bf16x4*>(sChunk(S, hh * 16 + r, j) + half * 8) = ot[hh];
    }
#pragma unroll
    for (int off = 1; off < 32; off <<= 1)
#pragma unroll
      for (int hh = 0; hh < 8; ++hh) psum[hh] += __shfl_xor(psum[hh], off);
    if (j == 0) {
#pragma unroll
      for (int hh = 0; hh < 8; ++hh) invS[hh * 16 + r] = 1.0f / psum[hh];
    }
  }
  __syncthreads();

  // ---- edge gather: ea = exp * inv ----
  {
    const int* ei = eidx + b * 4096;
#pragma unroll
    for (int jj = 0; jj < 4; ++jj) {
      int e = jj * 512 + tid;
      int s = ei[e];
      int t = ei[2048 + e];
      int rr = s - r0;
      if ((unsigned)rr < 16u) {
#pragma unroll
        for (int hh = 0; hh < 8; ++hh) {
          float a = bf2f(*reinterpret_cast<const short*>(sPtr(S, hh * 16 + rr, t))) * invS[hh * 16 + rr];
          ea[hh * 131072 + b * 2048 + e] = a;
        }
      }
    }
  }

  // ---- PV: Y = exp @ v ; U = v - Y*inv[row] ----
  {
    bf16x8 af[8];
#pragma unroll
    for (int ks = 0; ks < 8; ++ks)
      af[ks] = *reinterpret_cast<const bf16x8*>(sChunk(S, h * 16 + l16, ks * 4 + l4));
    const short* vb = vt + (b * 8 + h) * 16384;
#pragma unroll
    for (int nt = 0; nt < 4; ++nt) {
      f32x4 acc = {0.f, 0.f, 0.f, 0.f};
#pragma unroll
      for (int ks = 0; ks < 8; ++ks) {
        bf16x8 bv = *reinterpret_cast<const bf16x8*>(vb + (nt * 16 + l16) * 256 + ks * 32 + l4 * 8);
        acc = __builtin_amdgcn_mfma_f32_16x16x32_bf16(af[ks], bv, acc, 0, 0, 0);
      }
      bf16x4 vv = *reinterpret_cast<const bf16x4*>(vb + (nt * 16 + l16) * 256 + r0 + l4 * 4);
#pragma unroll
      for (int i = 0; i < 4; ++i) {
        int rl = l4 * 4 + i;
        int row = b * 256 + r0 + rl;
        int col = h * 64 + nt * 16 + l16;
        U[row * 512 + col] = f2bf(bf2f(vv[i]) - acc[i] * invS[h * 16 + rl]);
      }
    }
  }
}

extern "C" void kernel_launch(void* const* d_in, const int* in_sizes, int n_in,
                              void* d_out, int out_size, void* d_ws, size_t ws_size,
                              hipStream_t stream) {
  const float* x = (const float*)d_in[0];
  const int* eidx = (const int*)d_in[1];
  const float* Wq = (const float*)d_in[2];
  const float* Wk = (const float*)d_in[3];
  const float* Wv = (const float*)d_in[4];
  const float* We = (const float*)d_in[5];
  const float* Ws = (const float*)d_in[6];
  const float* Wo = (const float*)d_in[7];
  const float* bo = (const float*)d_in[8];
  float* out = (float*)d_out;

  char* ws = (char*)d_ws;
  short* x_bf  = (short*)(ws);              // 16 MB (aliased with U after gemm<0>)
  short* w_qkv = (short*)(ws + 16777216);   // 1.5 MB  [Wq; Wk*0.125; Wv]
  short* w_o   = (short*)(ws + 18350080);   // 0.5 MB
  short* qk    = (short*)(ws + 18874368);   // 32 MB
  short* vt    = (short*)(ws + 52428800);   // 16 MB
  short* Ub    = x_bf;

  cast_kernel<<<8192, 256, 0, stream>>>(x, x_bf, 2097152, 1.0f);
  cast_kernel<<<256, 256, 0, stream>>>(Wq, w_qkv, 65536, 1.0f);
  cast_kernel<<<256, 256, 0, stream>>>(Wk, w_qkv + 262144, 65536, 0.125f);
  cast_kernel<<<256, 256, 0, stream>>>(Wv, w_qkv + 524288, 65536, 1.0f);
  cast_kernel<<<256, 256, 0, stream>>>(Wo, w_o, 65536, 1.0f);

  gemm_k512<0><<<1536, 256, 0, stream>>>(x_bf, w_qkv, 12, qk, vt, nullptr, nullptr);
  attn_fused<<<1024, 512, 0, stream>>>(qk, vt, We, Ws, eidx, Ub, out + 8388608);
  gemm_k512<1><<<512, 256, 0, stream>>>(Ub, w_o, 4, nullptr, nullptr, out, bo);
}